// Round 1
// baseline (227.753 us; speedup 1.0000x reference)
//
#include <hip/hip_runtime.h>

// Problem constants (from reference): N=50000, E=100000, F=80000, B=64, S=32, T=32, D=3
#define NB     64
#define SS     32
#define TT     32
#define RADIUS 1.1f
#define SHARP  500.0f
#define TC     4          // t-values per block
#define NCHUNK 128        // simplex chunks per t-chunk  -> grid = 8*128 = 1024 blocks
#define BAND   0.05f      // |lin[s]-h| <= BAND -> compute sigmoid exactly (500*0.05=25)

// LDS tile: delta-domain accumulator, layout [s][b][tc]  (32*64*4 floats = 32 KB)
#define TILE_ELEMS (SS * NB * TC)

__global__ __launch_bounds__(256) void wect_main(
    const float* __restrict__ x,      // [N,3]
    const float* __restrict__ nw,     // [N]
    const float* __restrict__ v,      // [3,T]
    const float* __restrict__ lin,    // [S]
    const int*   __restrict__ ei,     // [2,E]
    const int*   __restrict__ fc,     // [3,F]
    const int*   __restrict__ batch,  // [N]
    float*       __restrict__ out,    // [B,S,T] used as delta accumulator here
    int N, int E, int F)
{
    __shared__ float acc[TILE_ELEMS];

    const int tid    = threadIdx.x;
    const int tchunk = blockIdx.x & 7;      // 8 t-chunks of TC=4
    const int chunk  = blockIdx.x >> 3;     // 0..NCHUNK-1
    const int tc     = tid & 3;
    const int sid    = tid >> 2;            // 0..63 : simplex slot within iteration
    const int t      = tchunk * TC + tc;

    for (int i = tid; i < TILE_ELEMS; i += 256) acc[i] = 0.0f;
    __syncthreads();

    // v column for this thread's theta
    const float v0 = v[0 * TT + t];
    const float v1 = v[1 * TT + t];
    const float v2 = v[2 * TT + t];

    const float step     = (2.0f * RADIUS) / (float)(SS - 1);
    const float inv_step = 1.0f / step;

    const int TOTAL = N + E + F;
    for (int m = chunk * 64 + sid; m < TOTAL; m += 64 * NCHUNK) {
        float h, w, sgn;
        int b;
        if (m < N) {
            const float* xr = x + 3 * m;
            h = xr[0] * v0 + xr[1] * v1 + xr[2] * v2;
            w = nw[m];
            b = batch[m];
            sgn = 1.0f;
        } else if (m < N + E) {
            const int e  = m - N;
            const int i0 = ei[e];
            const int i1 = ei[E + e];
            const float* x0 = x + 3 * i0;
            const float* x1 = x + 3 * i1;
            const float h0 = x0[0] * v0 + x0[1] * v1 + x0[2] * v2;
            const float h1 = x1[0] * v0 + x1[1] * v1 + x1[2] * v2;
            h = fminf(h0, h1);
            w = fmaxf(nw[i0], nw[i1]);
            b = batch[i0];
            sgn = -1.0f;
        } else {
            const int f  = m - N - E;
            const int i0 = fc[f];
            const int i1 = fc[F + f];
            const int i2 = fc[2 * F + f];
            const float* x0 = x + 3 * i0;
            const float* x1 = x + 3 * i1;
            const float* x2 = x + 3 * i2;
            const float h0 = x0[0] * v0 + x0[1] * v1 + x0[2] * v2;
            const float h1 = x1[0] * v0 + x1[1] * v1 + x1[2] * v2;
            const float h2 = x2[0] * v0 + x2[1] * v1 + x2[2] * v2;
            h = fminf(h0, fminf(h1, h2));
            w = fmaxf(nw[i0], fmaxf(nw[i1], nw[i2]));
            b = batch[i0];
            sgn = 1.0f;
        }
        const float ws = sgn * w;

        // transition band: s in [sA, sB] exact; s >= sBr+1 fully saturated (sig==1)
        const float ulo = (h - BAND + RADIUS) * inv_step;
        const float uhi = (h + BAND + RADIUS) * inv_step;
        int sA  = (int)ceilf(ulo);  if (sA < 0) sA = 0;
        const int sBr = (int)floorf(uhi);
        int sB  = sBr; if (sB > SS - 1) sB = SS - 1;

        // exact region: at most 2 iterations (band width 0.10 / step 0.071 = 1.41)
        for (int s = sA; s <= sB; ++s) {
            const float z   = SHARP * (lin[s] - h);
            const float sig = 1.0f / (1.0f + __expf(-z));
            const float val = ws * sig;
            atomicAdd(&acc[(s * NB + b) * TC + tc], val);
            if (s + 1 < SS) atomicAdd(&acc[((s + 1) * NB + b) * TC + tc], -val);
        }
        // suffix: all s >= sfx get the full weight
        int sfx = sBr + 1; if (sfx < 0) sfx = 0;
        if (sfx < SS) atomicAdd(&acc[(sfx * NB + b) * TC + tc], ws);
    }
    __syncthreads();

    // flush LDS tile to global delta buffer (resides in d_out)
    for (int i = tid; i < TILE_ELEMS; i += 256) {
        const float vv = acc[i];
        if (vv != 0.0f) {
            const int s   = i >> 8;        // i / (NB*TC)
            const int b   = (i >> 2) & 63; // (i / TC) % NB
            const int tcc = i & 3;
            atomicAdd(&out[(b * SS + s) * TT + tchunk * TC + tcc], vv);
        }
    }
}

// In-place prefix sum over s for each (b, t) column: out[b][s][t] = sum_{s'<=s} delta
__global__ __launch_bounds__(256) void wect_prefix(float* __restrict__ out)
{
    const int idx = blockIdx.x * 256 + threadIdx.x;   // 0..2047
    if (idx >= NB * TT) return;
    const int b = idx >> 5;   // /32
    const int t = idx & 31;
    float run = 0.0f;
    float* p = out + b * SS * TT + t;
#pragma unroll
    for (int s = 0; s < SS; ++s) {
        run += p[s * TT];
        p[s * TT] = run;
    }
}

extern "C" void kernel_launch(void* const* d_in, const int* in_sizes, int n_in,
                              void* d_out, int out_size, void* d_ws, size_t ws_size,
                              hipStream_t stream)
{
    const float* x     = (const float*)d_in[0];
    const float* nw    = (const float*)d_in[1];
    const float* v     = (const float*)d_in[2];
    const float* lin   = (const float*)d_in[3];
    const int*   ei    = (const int*)d_in[4];
    const int*   fc    = (const int*)d_in[5];
    const int*   batch = (const int*)d_in[6];
    float*       out   = (float*)d_out;

    const int N = in_sizes[1];       // node_weights
    const int E = in_sizes[4] / 2;   // edge_index [2,E]
    const int F = in_sizes[5] / 3;   // face [3,F]

    // zero the output (used as delta-domain accumulator) every call
    hipMemsetAsync(out, 0, (size_t)out_size * sizeof(float), stream);

    wect_main<<<8 * NCHUNK, 256, 0, stream>>>(x, nw, v, lin, ei, fc, batch, out, N, E, F);
    wect_prefix<<<(NB * TT + 255) / 256, 256, 0, stream>>>(out);
}

// Round 2
// 160.248 us; speedup vs baseline: 1.4213x; 1.4213x over previous
//
#include <hip/hip_runtime.h>

// Problem constants: N=50000, E=100000, F=80000, B=64, S=32, T=32, D=3
#define NB     64
#define SS     32
#define TT     32
#define RADIUS 1.1f
#define SHARP  500.0f
#define TC     4                    // t-values per block
#define NTCH   8                    // t-chunks (TT/TC)
#define BAND   0.05f                // exact-sigmoid band half-width (500*0.05=25)
#define CELLS  (SS * NB * TC)       // 8192 cells per t-chunk tile
#define NWAYS  8                    // chunk-reduction fan-in ways

__global__ __launch_bounds__(256) void wect_main(
    const float* __restrict__ x,      // [N,3]
    const float* __restrict__ nw,     // [N]
    const float* __restrict__ v,      // [3,T]
    const float* __restrict__ lin,    // [S]
    const int*   __restrict__ ei,     // [2,E]
    const int*   __restrict__ fc,     // [3,F]
    const int*   __restrict__ batch,  // [N]
    float*       __restrict__ partial,// [nchunk*8][CELLS] (ws) or nullptr
    float*       __restrict__ out,    // [B,S,T] delta accumulator (fallback only)
    int N, int E, int F, int nchunk, int atomic_mode)
{
    __shared__ float acc[CELLS];

    const int tid    = threadIdx.x;
    const int tchunk = blockIdx.x & 7;
    const int chunk  = blockIdx.x >> 3;
    const int tc     = tid & 3;
    const int sid    = tid >> 2;
    const int t      = tchunk * TC + tc;

    for (int i = tid; i < CELLS; i += 256) acc[i] = 0.0f;
    __syncthreads();

    const float v0 = v[0 * TT + t];
    const float v1 = v[1 * TT + t];
    const float v2 = v[2 * TT + t];

    const float step     = (2.0f * RADIUS) / (float)(SS - 1);
    const float inv_step = 1.0f / step;

    const int TOTAL  = N + E + F;
    const int stride = 64 * nchunk;
    for (int m = chunk * 64 + sid; m < TOTAL; m += stride) {
        float h, w, sgn;
        int b;
        if (m < N) {
            const float* xr = x + 3 * m;
            h = xr[0] * v0 + xr[1] * v1 + xr[2] * v2;
            w = nw[m];
            b = batch[m];
            sgn = 1.0f;
        } else if (m < N + E) {
            const int e  = m - N;
            const int i0 = ei[e];
            const int i1 = ei[E + e];
            const float* x0 = x + 3 * i0;
            const float* x1 = x + 3 * i1;
            const float h0 = x0[0] * v0 + x0[1] * v1 + x0[2] * v2;
            const float h1 = x1[0] * v0 + x1[1] * v1 + x1[2] * v2;
            h = fminf(h0, h1);
            w = fmaxf(nw[i0], nw[i1]);
            b = batch[i0];
            sgn = -1.0f;
        } else {
            const int f  = m - N - E;
            const int i0 = fc[f];
            const int i1 = fc[F + f];
            const int i2 = fc[2 * F + f];
            const float* x0 = x + 3 * i0;
            const float* x1 = x + 3 * i1;
            const float* x2 = x + 3 * i2;
            const float h0 = x0[0] * v0 + x0[1] * v1 + x0[2] * v2;
            const float h1 = x1[0] * v0 + x1[1] * v1 + x1[2] * v2;
            const float h2 = x2[0] * v0 + x2[1] * v1 + x2[2] * v2;
            h = fminf(h0, fminf(h1, h2));
            w = fmaxf(nw[i0], fmaxf(nw[i1], nw[i2]));
            b = batch[i0];
            sgn = 1.0f;
        }
        const float ws = sgn * w;

        const float ulo = (h - BAND + RADIUS) * inv_step;
        const float uhi = (h + BAND + RADIUS) * inv_step;
        int sA = (int)ceilf(ulo);  if (sA < 0) sA = 0;
        const int sBr = (int)floorf(uhi);
        int sB = sBr; if (sB > SS - 1) sB = SS - 1;

        for (int s = sA; s <= sB; ++s) {
            const float z   = SHARP * (lin[s] - h);
            const float sig = 1.0f / (1.0f + __expf(-z));
            const float val = ws * sig;
            atomicAdd(&acc[(s * NB + b) * TC + tc], val);
            if (s + 1 < SS) atomicAdd(&acc[((s + 1) * NB + b) * TC + tc], -val);
        }
        int sfx = sBr + 1; if (sfx < 0) sfx = 0;
        if (sfx < SS) atomicAdd(&acc[(sfx * NB + b) * TC + tc], ws);
    }
    __syncthreads();

    if (!atomic_mode) {
        // plain coalesced store of the whole tile into the partial buffer
        float* dst = partial + (size_t)blockIdx.x * CELLS;
        for (int i = tid; i < CELLS; i += 256) dst[i] = acc[i];
    } else {
        for (int i = tid; i < CELLS; i += 256) {
            const float vv = acc[i];
            if (vv != 0.0f) {
                const int s   = i >> 8;
                const int b   = (i >> 2) & 63;
                const int tcc = i & 3;
                atomicAdd(&out[(b * SS + s) * TT + tchunk * TC + tcc], vv);
            }
        }
    }
}

// Stage A: fold nchunk chunks down to NWAYS partials per (tchunk, cell).
// grid: NTCH * NWAYS * (CELLS/256) blocks of 256 threads.
__global__ __launch_bounds__(256) void wect_reduce1(
    const float* __restrict__ partial, float* __restrict__ ws2, int nchunk)
{
    const int cellblk = blockIdx.x & 31;          // CELLS/256 = 32
    const int way     = (blockIdx.x >> 5) & 7;
    const int tchunk  = blockIdx.x >> 8;
    const int cell    = cellblk * 256 + threadIdx.x;

    float s = 0.0f;
    for (int c = way; c < nchunk; c += NWAYS)
        s += partial[((size_t)(c * NTCH + tchunk)) * CELLS + cell];
    ws2[((size_t)(tchunk * NWAYS + way)) * CELLS + cell] = s;
}

// Stage B: fold NWAYS ways, scatter delta into out[b][s][t].
__global__ __launch_bounds__(256) void wect_reduce2(
    const float* __restrict__ ws2, float* __restrict__ out)
{
    const int idx    = blockIdx.x * 256 + threadIdx.x;   // 0 .. NTCH*CELLS-1
    const int tchunk = idx >> 13;                        // / CELLS
    const int cell   = idx & (CELLS - 1);

    float s = 0.0f;
#pragma unroll
    for (int w = 0; w < NWAYS; ++w)
        s += ws2[((size_t)(tchunk * NWAYS + w)) * CELLS + cell];

    const int ss  = cell >> 8;
    const int b   = (cell >> 2) & 63;
    const int tcc = cell & 3;
    out[(b * SS + ss) * TT + tchunk * TC + tcc] = s;
}

// In-place prefix sum over s for each (b, t) column.
__global__ __launch_bounds__(256) void wect_prefix(float* __restrict__ out)
{
    const int idx = blockIdx.x * 256 + threadIdx.x;
    if (idx >= NB * TT) return;
    const int b = idx >> 5;
    const int t = idx & 31;
    float run = 0.0f;
    float* p = out + b * SS * TT + t;
#pragma unroll
    for (int s = 0; s < SS; ++s) {
        run += p[s * TT];
        p[s * TT] = run;
    }
}

extern "C" void kernel_launch(void* const* d_in, const int* in_sizes, int n_in,
                              void* d_out, int out_size, void* d_ws, size_t ws_size,
                              hipStream_t stream)
{
    const float* x     = (const float*)d_in[0];
    const float* nw    = (const float*)d_in[1];
    const float* v     = (const float*)d_in[2];
    const float* lin   = (const float*)d_in[3];
    const int*   ei    = (const int*)d_in[4];
    const int*   fc    = (const int*)d_in[5];
    const int*   batch = (const int*)d_in[6];
    float*       out   = (float*)d_out;

    const int N = in_sizes[1];
    const int E = in_sizes[4] / 2;
    const int F = in_sizes[5] / 3;

    // ws layout: [partial: 8*nchunk*CELLS floats][ws2: 8*NWAYS*CELLS floats]
    const size_t ws2_bytes  = (size_t)NTCH * NWAYS * CELLS * sizeof(float); // 2 MB
    const size_t unit_bytes = (size_t)NTCH * CELLS * sizeof(float);         // 256 KB per chunk
    int nchunk = 0;
    if (ws_size > ws2_bytes)
        nchunk = (int)((ws_size - ws2_bytes) / unit_bytes);
    if (nchunk > 128) nchunk = 128;

    if (nchunk >= 4) {
        float* partial = (float*)d_ws;
        float* ws2     = (float*)((char*)d_ws + (size_t)nchunk * unit_bytes);
        wect_main<<<NTCH * nchunk, 256, 0, stream>>>(
            x, nw, v, lin, ei, fc, batch, partial, out, N, E, F, nchunk, 0);
        wect_reduce1<<<NTCH * NWAYS * (CELLS / 256), 256, 0, stream>>>(partial, ws2, nchunk);
        wect_reduce2<<<NTCH * CELLS / 256, 256, 0, stream>>>(ws2, out);
    } else {
        // fallback: atomic flush directly into out (delta domain)
        hipMemsetAsync(out, 0, (size_t)out_size * sizeof(float), stream);
        wect_main<<<NTCH * 128, 256, 0, stream>>>(
            x, nw, v, lin, ei, fc, batch, nullptr, out, N, E, F, 128, 1);
    }
    wect_prefix<<<(NB * TT + 255) / 256, 256, 0, stream>>>(out);
}